// Round 8
// baseline (785.352 us; speedup 1.0000x reference)
//
#include <hip/hip_runtime.h>
#include <math.h>

#define D   128
#define LQ  256
#define KCQ 9
#define BQ  8
#define TQ  4096
#define RISK_DELTA 2e-5f
#define WCAP 16384

// ---------------- pk1: T2 = Wk^T@Wq, u = ctx_w^T@bias_w^T, transposed f32 tables ----
__global__ void pk1(const float* __restrict__ wk, const float* __restrict__ wq,
                    const float* __restrict__ ctx_w, const float* __restrict__ bias_w,
                    const float* __restrict__ conv_w, const float* __restrict__ val_b,
                    const float* __restrict__ lag_embed,
                    double* __restrict__ T2, double* __restrict__ u, int* __restrict__ wcnt,
                    float* __restrict__ ctx_wT, float* __restrict__ wqT,
                    float* __restrict__ conv_wT, float* __restrict__ baseT) {
    int tid = threadIdx.x;
    int bid = blockIdx.x;
    if (bid < D) {
        int d = bid;
        if (tid < D) {
            double acc = 0.0;
            for (int j = 0; j < D; ++j)
                acc += (double)wk[j * D + d] * (double)wq[j * D + tid];
            T2[d * D + tid] = acc;
            ctx_wT[d * D + tid] = ctx_w[tid * D + d];
            wqT[d * D + tid]    = wq[tid * D + d];
            if (d < KCQ) conv_wT[d * D + tid] = conv_w[tid * KCQ + d];
        }
        // baseT[d][l] = f32(val_b[d] + lag_embed[l+1][d])
        baseT[d * LQ + tid] = __fadd_rn(val_b[d], lag_embed[(size_t)(tid + 1) * D + d]);
    } else if (bid == D) {
        if (tid < D) {
            double acc = 0.0;
            for (int dd = 0; dd < D; ++dd)
                acc += (double)bias_w[dd] * (double)ctx_w[dd * D + tid];
            u[tid] = acc;
        }
    } else {
        if (tid == 0) *wcnt = 0;
    }
}

__global__ void pk2(const double* __restrict__ T2, const float* __restrict__ ctx_w,
                    const float* __restrict__ conv_w, const float* __restrict__ conv_b,
                    const float* __restrict__ ctx_b,
                    double* __restrict__ g, double* __restrict__ c1) {
    __shared__ double row[D];
    int d = blockIdx.x, e = threadIdx.x;
    double acc = 0.0;
    for (int j = 0; j < D; ++j)
        acc += T2[d * D + j] * (double)ctx_w[j * D + e];
    row[e] = acc;
    __syncthreads();
    if (e < KCQ) {
        double a = 0.0;
        for (int q = 0; q < D; ++q) a += row[q] * (double)conv_w[q * KCQ + e];
        g[e * D + d] = a;           // tap-major: g[k][d]
    } else if (e == KCQ) {
        double a = 0.0;
        for (int q = 0; q < D; ++q) a += row[q] * (double)conv_b[q];
        for (int q = 0; q < D; ++q) a += T2[d * D + q] * (double)ctx_b[q];
        c1[d] = a;
    }
}

__global__ void pk3(const float* __restrict__ lag_embed, const float* __restrict__ val_b,
                    const float* __restrict__ val_w, const float* __restrict__ conv_w,
                    const float* __restrict__ conv_b, const float* __restrict__ ctx_b,
                    const float* __restrict__ bias_w, const float* __restrict__ bias_b,
                    const double* __restrict__ g, const double* __restrict__ c1,
                    const double* __restrict__ u,
                    double* __restrict__ gbT, double* __restrict__ cbv, double* __restrict__ cst) {
    int tid = threadIdx.x;
    if (blockIdx.x < LQ) {
        __shared__ double bl[D];
        int l = blockIdx.x;
        bl[tid] = (double)val_b[tid] + (double)lag_embed[(l + 1) * D + tid];
        __syncthreads();
        if (tid < KCQ) {
            double a = 0.0;
            for (int q = 0; q < D; ++q) a += bl[q] * g[tid * D + q];
            gbT[tid * LQ + l] = a;
        } else if (tid == KCQ) {
            double a = 0.0;
            for (int q = 0; q < D; ++q) a += bl[q] * c1[q];
            cbv[l] = a;
        }
    } else {
        if (tid < KCQ) {
            double a = 0.0, a2 = 0.0;
            for (int q = 0; q < D; ++q) a  += g[tid * D + q] * (double)val_w[q];
            for (int q = 0; q < D; ++q) a2 += u[q] * (double)conv_w[q * KCQ + tid];
            cst[tid]      = a;    // sk[k]
            cst[10 + tid] = a2;   // hk[k]
        } else if (tid == KCQ) {
            double a = 0.0, a2 = 0.0;
            for (int q = 0; q < D; ++q) a  += c1[q] * (double)val_w[q];
            for (int q = 0; q < D; ++q) a2 += u[q] * (double)conv_b[q];
            for (int q = 0; q < D; ++q) a2 += (double)bias_w[q] * (double)ctx_b[q];
            cst[9]  = a;                          // ssc
            cst[19] = a2 + (double)bias_b[0];     // hc (incl. bias_b)
        }
    }
}

// ---------------- main kernel (round-5 version, verbatim): 1 wave per row ----------
__global__ __launch_bounds__(256, 4) void lag_main(
    const float* __restrict__ x, const double* __restrict__ gbT,
    const double* __restrict__ cbv, const double* __restrict__ cst,
    float* __restrict__ muOut, float* __restrict__ wOut,
    int* __restrict__ wcnt, int* __restrict__ wlist) {
    __shared__ float sgb[KCQ * LQ];
    __shared__ float scb[LQ];
    __shared__ float sc[20];
    int tid = threadIdx.x;
    #pragma unroll
    for (int i = 0; i < KCQ; ++i) sgb[i * LQ + tid] = (float)gbT[i * LQ + tid];
    scb[tid] = (float)cbv[tid];
    if (tid < 20) sc[tid] = (float)cst[tid];
    __syncthreads();

    int wave = tid >> 6, lane = tid & 63;
    int row = blockIdx.x * 4 + wave;
    int b = row >> 12;
    int t = row & (TQ - 1);
    const float* xb = x + b * TQ;

    float xw[KCQ];
    #pragma unroll
    for (int k = 0; k < KCQ; ++k) {
        int idx = t - 8 + k;
        xw[k] = (idx >= 0) ? xb[idx] : 0.f;
    }
    float s = sc[9], bias = sc[19];
    #pragma unroll
    for (int k = 0; k < KCQ; ++k) {
        s    = fmaf(sc[k],      xw[k], s);
        bias = fmaf(sc[10 + k], xw[k], bias);
    }

    int l0 = lane * 4;
    float xlag[4];
    #pragma unroll
    for (int i = 0; i < 4; ++i) {
        int idx = t - 1 - (l0 + i);
        xlag[i] = (idx >= 0) ? xb[idx] : 0.f;
    }

    float4 cb4 = *reinterpret_cast<const float4*>(&scb[l0]);
    float lg[4] = {cb4.x, cb4.y, cb4.z, cb4.w};
    #pragma unroll
    for (int k = 0; k < KCQ; ++k) {
        float4 g4 = *reinterpret_cast<const float4*>(&sgb[k * LQ + l0]);
        lg[0] = fmaf(g4.x, xw[k], lg[0]);
        lg[1] = fmaf(g4.y, xw[k], lg[1]);
        lg[2] = fmaf(g4.z, xw[k], lg[2]);
        lg[3] = fmaf(g4.w, xw[k], lg[3]);
    }
    #pragma unroll
    for (int i = 0; i < 4; ++i) lg[i] = fmaf(xlag[i], s, lg[i]);

    // top-9 extraction (f32): v1 (mx), v8 (thr), v9 (risk gap)
    const float NEG_INF = -__builtin_inff();
    float wl0 = lg[0], wl1 = lg[1], wl2 = lg[2], wl3 = lg[3];
    float mx = 0.f, thr = 0.f, v9 = 0.f;
    #pragma unroll
    for (int it = 0; it < 9; ++it) {
        float lm = fmaxf(fmaxf(wl0, wl1), fmaxf(wl2, wl3));
        float m = lm;
        #pragma unroll
        for (int off = 32; off >= 1; off >>= 1)
            m = fmaxf(m, __shfl_xor(m, off, 64));
        if (it == 0) mx = m;
        if (it == 7) thr = m;
        if (it == 8) v9 = m;
        if (it < 8) {
            unsigned long long ball = __ballot(lm == m);
            int leader = __ffsll(ball) - 1;
            if (lane == leader) {
                if (wl0 == m)      wl0 = NEG_INF;
                else if (wl1 == m) wl1 = NEG_INF;
                else if (wl2 == m) wl2 = NEG_INF;
                else               wl3 = NEG_INF;
            }
        }
    }

    if ((thr - v9) < RISK_DELTA) {
        if (lane == 0) {
            int pos = atomicAdd(wcnt, 1);
            if (pos < WCAP) wlist[pos] = row;
        }
        return;
    }

    float p[4], psum = 0.f, pmu = 0.f;
    #pragma unroll
    for (int j = 0; j < 4; ++j) {
        p[j] = (lg[j] >= thr) ? __expf(lg[j] - mx) : 0.f;
        psum += p[j];
        pmu = fmaf(p[j], xlag[j], pmu);
    }
    #pragma unroll
    for (int off = 32; off >= 1; off >>= 1) {
        psum += __shfl_xor(psum, off, 64);
        pmu  += __shfl_xor(pmu,  off, 64);
    }
    float inv = 1.f / psum;
    float4 wo = make_float4(p[0] * inv, p[1] * inv, p[2] * inv, p[3] * inv);
    *reinterpret_cast<float4*>(&wOut[(size_t)row * LQ + l0]) = wo;
    if (lane == 0) muOut[row] = fmaf(pmu, inv, bias);
}

// ---------------- fixer: np-faithful fp32 pipeline, ONE ROW PER BLOCK --------------
// Arithmetic bit-identical to the round-4/5/7 arbiter-matcher (sequential f32 FMA,
// ascending index; __fadd_rn/__fmul_rn at materialization points). Restructured for
// parallelism: 256 threads per row-block, single accumulator per thread (no spills).
__global__ __launch_bounds__(256) void fixer(
    const float* __restrict__ x, const float* __restrict__ wk,
    const float* __restrict__ val_w, const float* __restrict__ conv_b,
    const float* __restrict__ ctx_b, const float* __restrict__ bias_w,
    const float* __restrict__ bias_b,
    const float* __restrict__ ctx_wT, const float* __restrict__ wqT,
    const float* __restrict__ conv_wT, const float* __restrict__ baseT,
    const int* __restrict__ wcnt, const int* __restrict__ wlist,
    float* __restrict__ muOut, float* __restrict__ wOut) {
    __shared__ float sxw[KCQ];
    __shared__ float sctxc[D];
    __shared__ float sctxp[D];
    __shared__ float sq[D];
    __shared__ float sqk[D];
    __shared__ float ssv1, sbd1;
    __shared__ float slog[LQ];

    int cnt = *wcnt;
    if (cnt > WCAP) cnt = WCAP;
    int tid = threadIdx.x;

    for (int ri = blockIdx.x; ri < cnt; ri += gridDim.x) {
        int row = wlist[ri];
        int b = row >> 12, t = row & (TQ - 1);
        const float* xb = x + b * TQ;
        if (tid < KCQ) {
            int ii = t - 8 + tid;
            sxw[tid] = (ii >= 0) ? xb[ii] : 0.f;
        }
        __syncthreads();

        // stage 1: causal conv (9 taps, ascending k) + conv_b
        if (tid < D) {
            float a = 0.f;
            #pragma unroll
            for (int k = 0; k < KCQ; ++k)
                a = fmaf(conv_wT[k * D + tid], sxw[k], a);
            sctxc[tid] = __fadd_rn(a, conv_b[tid]);
        }
        __syncthreads();

        // stage 2: ctx_proj — sequential FMA over d2 (16-wide coalesced load batches)
        if (tid < D) {
            float a = 0.f;
            for (int d2 = 0; d2 < D; d2 += 16) {
                float wv[16];
                #pragma unroll
                for (int u = 0; u < 16; ++u) wv[u] = ctx_wT[(d2 + u) * D + tid];
                #pragma unroll
                for (int u = 0; u < 16; ++u) a = fmaf(wv[u], sctxc[d2 + u], a);
            }
            sctxp[tid] = __fadd_rn(a, ctx_b[tid]);
        }
        __syncthreads();

        // stage 3: q = ctx @ wq.T ; sbd (needs only sctxp) hidden on idle thread 128
        if (tid < D) {
            float a = 0.f;
            for (int e2 = 0; e2 < D; e2 += 16) {
                float wv[16];
                #pragma unroll
                for (int u = 0; u < 16; ++u) wv[u] = wqT[(e2 + u) * D + tid];
                #pragma unroll
                for (int u = 0; u < 16; ++u) a = fmaf(wv[u], sctxp[e2 + u], a);
            }
            sq[tid] = a;
        } else if (tid == D) {
            float a = 0.f;
            for (int e2 = 0; e2 < D; ++e2) a = fmaf(sctxp[e2], bias_w[e2], a);
            sbd1 = a;
        }
        __syncthreads();

        // stage 4: qk = q @ wk
        if (tid < D) {
            float a = 0.f;
            for (int a2 = 0; a2 < D; a2 += 16) {
                float wv[16];
                #pragma unroll
                for (int u = 0; u < 16; ++u) wv[u] = wk[(a2 + u) * D + tid];
                #pragma unroll
                for (int u = 0; u < 16; ++u) a = fmaf(wv[u], sq[a2 + u], a);
            }
            sqk[tid] = a;
        }
        __syncthreads();

        // logits dot (tid<128 handles l=tid and l=tid+128); ssv on idle thread 128
        if (tid < D) {
            int la = tid, lb = tid + 128;
            float c0 = 0.f, c1v = 0.f;
            for (int d2 = 0; d2 < D; d2 += 16) {
                float b0[16], b1[16];
                #pragma unroll
                for (int u = 0; u < 16; ++u) {
                    b0[u] = baseT[(d2 + u) * LQ + la];
                    b1[u] = baseT[(d2 + u) * LQ + lb];
                }
                #pragma unroll
                for (int u = 0; u < 16; ++u) {
                    float qv = sqk[d2 + u];
                    c0  = fmaf(b0[u], qv, c0);
                    c1v = fmaf(b1[u], qv, c1v);
                }
            }
            slog[la] = c0;
            slog[lb] = c1v;
        } else if (tid == D) {
            float a = 0.f;
            for (int d2 = 0; d2 < D; ++d2) a = fmaf(sqk[d2], val_w[d2], a);
            ssv1 = a;
        }
        __syncthreads();

        // combine: logit = f32(xlag * s) + blog
        {
            int l = tid;
            int ii = t - 1 - l;
            float xl = (ii >= 0) ? xb[ii] : 0.f;
            slog[l] = __fadd_rn(__fmul_rn(xl, ssv1), slog[l]);
        }
        __syncthreads();

        // wave 0: f32 top-8 + f32 softmax + writes (identical ladder/semantics)
        if (tid < 64) {
            int lane = tid;
            float lv0 = slog[lane], lv1 = slog[lane + 64];
            float lv2 = slog[lane + 128], lv3 = slog[lane + 192];
            const float NEG_INF = -__builtin_inff();
            float w0 = lv0, w1 = lv1, w2 = lv2, w3 = lv3;
            float mx = 0.f, thr = 0.f;
            #pragma unroll
            for (int it = 0; it < 8; ++it) {
                float lm = fmaxf(fmaxf(w0, w1), fmaxf(w2, w3));
                float m = lm;
                #pragma unroll
                for (int off = 32; off >= 1; off >>= 1)
                    m = fmaxf(m, __shfl_xor(m, off, 64));
                if (it == 0) mx = m;
                thr = m;
                if (it < 7) {
                    unsigned long long ball = __ballot(lm == m);
                    int leader = __ffsll(ball) - 1;
                    if (lane == leader) {
                        if (w0 == m)      w0 = NEG_INF;
                        else if (w1 == m) w1 = NEG_INF;
                        else if (w2 == m) w2 = NEG_INF;
                        else              w3 = NEG_INF;
                    }
                }
            }
            float p[4], xlg[4];
            double ps = 0.0;
            float lvs[4] = {lv0, lv1, lv2, lv3};
            #pragma unroll
            for (int j = 0; j < 4; ++j) {
                int l = lane + 64 * j;
                int ii = t - 1 - l;
                xlg[j] = (ii >= 0) ? xb[ii] : 0.f;
                p[j] = (lvs[j] >= thr) ? (float)exp((double)__fsub_rn(lvs[j], mx)) : 0.f;
                ps += (double)p[j];
            }
            #pragma unroll
            for (int off = 32; off >= 1; off >>= 1)
                ps += __shfl_xor(ps, off, 64);
            float psf = (float)ps;
            double mud = 0.0;
            #pragma unroll
            for (int j = 0; j < 4; ++j) {
                float wv = __fdiv_rn(p[j], psf);
                wOut[(size_t)row * LQ + lane + 64 * j] = wv;
                mud += (double)__fmul_rn(wv, xlg[j]);
            }
            #pragma unroll
            for (int off = 32; off >= 1; off >>= 1)
                mud += __shfl_xor(mud, off, 64);
            if (lane == 0) {
                float m1 = (float)mud;
                m1 = __fadd_rn(m1, sbd1);
                m1 = __fadd_rn(m1, bias_b[0]);
                muOut[row] = m1;
            }
        }
        __syncthreads();
    }
}

extern "C" void kernel_launch(void* const* d_in, const int* in_sizes, int n_in,
                              void* d_out, int out_size, void* d_ws, size_t ws_size,
                              hipStream_t stream) {
    const float* x         = (const float*)d_in[0];
    const float* lag_embed = (const float*)d_in[1];
    const float* val_w     = (const float*)d_in[2];
    const float* val_b     = (const float*)d_in[3];
    const float* conv_w    = (const float*)d_in[4];
    const float* conv_b    = (const float*)d_in[5];
    const float* ctx_w     = (const float*)d_in[6];
    const float* ctx_b     = (const float*)d_in[7];
    const float* wq        = (const float*)d_in[8];
    const float* wk        = (const float*)d_in[9];
    const float* bias_w    = (const float*)d_in[10];
    const float* bias_b    = (const float*)d_in[11];

    char* wsb = (char*)d_ws;
    double* T2  = (double*)wsb;     // 16384 d
    double* g   = T2 + 16384;       // 1152
    double* u   = g + 1152;         // 128
    double* c1  = u + 128;          // 128
    double* gbT = c1 + 128;         // 2304
    double* cbv = gbT + 2304;       // 256
    double* cst = cbv + 256;        // 20   (f64 region ends @ byte 162976)
    int* wcnt  = (int*)(wsb + 163840);
    int* wlist = wcnt + 1;          // WCAP=16384 ints
    float* ctx_wT  = (float*)(wsb + 229504);   // 16384 f
    float* wqT     = ctx_wT + 16384;           // 16384 f
    float* conv_wT = wqT + 16384;              // 1152 f
    float* baseT   = conv_wT + 1152;           // 32768 f, ends @ byte 496256

    float* muOut = (float*)d_out;
    float* wOut  = muOut + BQ * TQ;

    hipLaunchKernelGGL(pk1, dim3(D + 2), dim3(256), 0, stream,
                       wk, wq, ctx_w, bias_w, conv_w, val_b, lag_embed,
                       T2, u, wcnt, ctx_wT, wqT, conv_wT, baseT);
    hipLaunchKernelGGL(pk2, dim3(D), dim3(D), 0, stream, T2, ctx_w, conv_w, conv_b, ctx_b, g, c1);
    hipLaunchKernelGGL(pk3, dim3(LQ + 1), dim3(D), 0, stream,
                       lag_embed, val_b, val_w, conv_w, conv_b, ctx_b, bias_w, bias_b,
                       g, c1, u, gbT, cbv, cst);
    hipLaunchKernelGGL(lag_main, dim3(BQ * TQ / 4), dim3(256), 0, stream,
                       x, gbT, cbv, cst, muOut, wOut, wcnt, wlist);
    hipLaunchKernelGGL(fixer, dim3(1024), dim3(256), 0, stream,
                       x, wk, val_w, conv_b, ctx_b, bias_w, bias_b,
                       ctx_wT, wqT, conv_wT, baseT, wcnt, wlist, muOut, wOut);
}

// Round 9
// 100.990 us; speedup vs baseline: 7.7766x; 7.7766x over previous
//
#include <hip/hip_runtime.h>
#include <math.h>

#define D   128
#define LQ  256
#define KCQ 9
#define BQ  8
#define TQ  4096
#define RISK_DELTA 2e-5f
#define WCAP 16384

// ---------------- pk1: T2 = Wk^T@Wq, u = ctx_w^T@bias_w^T, transposed f32 tables ----
__global__ void pk1(const float* __restrict__ wk, const float* __restrict__ wq,
                    const float* __restrict__ ctx_w, const float* __restrict__ bias_w,
                    const float* __restrict__ conv_w, const float* __restrict__ val_b,
                    const float* __restrict__ lag_embed,
                    double* __restrict__ T2, double* __restrict__ u, int* __restrict__ wcnt,
                    float* __restrict__ ctx_wT, float* __restrict__ wqT,
                    float* __restrict__ conv_wT, float* __restrict__ baseT) {
    int tid = threadIdx.x;
    int bid = blockIdx.x;
    if (bid < D) {
        int d = bid;
        if (tid < D) {
            double acc = 0.0;
            for (int j = 0; j < D; ++j)
                acc += (double)wk[j * D + d] * (double)wq[j * D + tid];
            T2[d * D + tid] = acc;
            ctx_wT[d * D + tid] = ctx_w[tid * D + d];
            wqT[d * D + tid]    = wq[tid * D + d];
            if (d < KCQ) conv_wT[d * D + tid] = conv_w[tid * KCQ + d];
        }
        // baseT[d][l] = f32(val_b[d] + lag_embed[l+1][d])
        baseT[d * LQ + tid] = __fadd_rn(val_b[d], lag_embed[(size_t)(tid + 1) * D + d]);
    } else if (bid == D) {
        if (tid < D) {
            double acc = 0.0;
            for (int dd = 0; dd < D; ++dd)
                acc += (double)bias_w[dd] * (double)ctx_w[dd * D + tid];
            u[tid] = acc;
        }
    } else {
        if (tid == 0) *wcnt = 0;
    }
}

__global__ void pk2(const double* __restrict__ T2, const float* __restrict__ ctx_w,
                    const float* __restrict__ conv_w, const float* __restrict__ conv_b,
                    const float* __restrict__ ctx_b,
                    double* __restrict__ g, double* __restrict__ c1) {
    __shared__ double row[D];
    int d = blockIdx.x, e = threadIdx.x;
    double acc = 0.0;
    for (int j = 0; j < D; ++j)
        acc += T2[d * D + j] * (double)ctx_w[j * D + e];
    row[e] = acc;
    __syncthreads();
    if (e < KCQ) {
        double a = 0.0;
        for (int q = 0; q < D; ++q) a += row[q] * (double)conv_w[q * KCQ + e];
        g[e * D + d] = a;           // tap-major: g[k][d]
    } else if (e == KCQ) {
        double a = 0.0;
        for (int q = 0; q < D; ++q) a += row[q] * (double)conv_b[q];
        for (int q = 0; q < D; ++q) a += T2[d * D + q] * (double)ctx_b[q];
        c1[d] = a;
    }
}

__global__ void pk3(const float* __restrict__ lag_embed, const float* __restrict__ val_b,
                    const float* __restrict__ val_w, const float* __restrict__ conv_w,
                    const float* __restrict__ conv_b, const float* __restrict__ ctx_b,
                    const float* __restrict__ bias_w, const float* __restrict__ bias_b,
                    const double* __restrict__ g, const double* __restrict__ c1,
                    const double* __restrict__ u,
                    double* __restrict__ gbT, double* __restrict__ cbv, double* __restrict__ cst) {
    int tid = threadIdx.x;
    if (blockIdx.x < LQ) {
        __shared__ double bl[D];
        int l = blockIdx.x;
        bl[tid] = (double)val_b[tid] + (double)lag_embed[(l + 1) * D + tid];
        __syncthreads();
        if (tid < KCQ) {
            double a = 0.0;
            for (int q = 0; q < D; ++q) a += bl[q] * g[tid * D + q];
            gbT[tid * LQ + l] = a;
        } else if (tid == KCQ) {
            double a = 0.0;
            for (int q = 0; q < D; ++q) a += bl[q] * c1[q];
            cbv[l] = a;
        }
    } else {
        if (tid < KCQ) {
            double a = 0.0, a2 = 0.0;
            for (int q = 0; q < D; ++q) a  += g[tid * D + q] * (double)val_w[q];
            for (int q = 0; q < D; ++q) a2 += u[q] * (double)conv_w[q * KCQ + tid];
            cst[tid]      = a;    // sk[k]
            cst[10 + tid] = a2;   // hk[k]
        } else if (tid == KCQ) {
            double a = 0.0, a2 = 0.0;
            for (int q = 0; q < D; ++q) a  += c1[q] * (double)val_w[q];
            for (int q = 0; q < D; ++q) a2 += u[q] * (double)conv_b[q];
            for (int q = 0; q < D; ++q) a2 += (double)bias_w[q] * (double)ctx_b[q];
            cst[9]  = a;                          // ssc
            cst[19] = a2 + (double)bias_b[0];     // hc (incl. bias_b)
        }
    }
}

// ---------------- main kernel (round-5 version, verbatim): 1 wave per row ----------
__global__ __launch_bounds__(256, 4) void lag_main(
    const float* __restrict__ x, const double* __restrict__ gbT,
    const double* __restrict__ cbv, const double* __restrict__ cst,
    float* __restrict__ muOut, float* __restrict__ wOut,
    int* __restrict__ wcnt, int* __restrict__ wlist) {
    __shared__ float sgb[KCQ * LQ];
    __shared__ float scb[LQ];
    __shared__ float sc[20];
    int tid = threadIdx.x;
    #pragma unroll
    for (int i = 0; i < KCQ; ++i) sgb[i * LQ + tid] = (float)gbT[i * LQ + tid];
    scb[tid] = (float)cbv[tid];
    if (tid < 20) sc[tid] = (float)cst[tid];
    __syncthreads();

    int wave = tid >> 6, lane = tid & 63;
    int row = blockIdx.x * 4 + wave;
    int b = row >> 12;
    int t = row & (TQ - 1);
    const float* xb = x + b * TQ;

    float xw[KCQ];
    #pragma unroll
    for (int k = 0; k < KCQ; ++k) {
        int idx = t - 8 + k;
        xw[k] = (idx >= 0) ? xb[idx] : 0.f;
    }
    float s = sc[9], bias = sc[19];
    #pragma unroll
    for (int k = 0; k < KCQ; ++k) {
        s    = fmaf(sc[k],      xw[k], s);
        bias = fmaf(sc[10 + k], xw[k], bias);
    }

    int l0 = lane * 4;
    float xlag[4];
    #pragma unroll
    for (int i = 0; i < 4; ++i) {
        int idx = t - 1 - (l0 + i);
        xlag[i] = (idx >= 0) ? xb[idx] : 0.f;
    }

    float4 cb4 = *reinterpret_cast<const float4*>(&scb[l0]);
    float lg[4] = {cb4.x, cb4.y, cb4.z, cb4.w};
    #pragma unroll
    for (int k = 0; k < KCQ; ++k) {
        float4 g4 = *reinterpret_cast<const float4*>(&sgb[k * LQ + l0]);
        lg[0] = fmaf(g4.x, xw[k], lg[0]);
        lg[1] = fmaf(g4.y, xw[k], lg[1]);
        lg[2] = fmaf(g4.z, xw[k], lg[2]);
        lg[3] = fmaf(g4.w, xw[k], lg[3]);
    }
    #pragma unroll
    for (int i = 0; i < 4; ++i) lg[i] = fmaf(xlag[i], s, lg[i]);

    // top-9 extraction (f32): v1 (mx), v8 (thr), v9 (risk gap)
    const float NEG_INF = -__builtin_inff();
    float wl0 = lg[0], wl1 = lg[1], wl2 = lg[2], wl3 = lg[3];
    float mx = 0.f, thr = 0.f, v9 = 0.f;
    #pragma unroll
    for (int it = 0; it < 9; ++it) {
        float lm = fmaxf(fmaxf(wl0, wl1), fmaxf(wl2, wl3));
        float m = lm;
        #pragma unroll
        for (int off = 32; off >= 1; off >>= 1)
            m = fmaxf(m, __shfl_xor(m, off, 64));
        if (it == 0) mx = m;
        if (it == 7) thr = m;
        if (it == 8) v9 = m;
        if (it < 8) {
            unsigned long long ball = __ballot(lm == m);
            int leader = __ffsll(ball) - 1;
            if (lane == leader) {
                if (wl0 == m)      wl0 = NEG_INF;
                else if (wl1 == m) wl1 = NEG_INF;
                else if (wl2 == m) wl2 = NEG_INF;
                else               wl3 = NEG_INF;
            }
        }
    }

    if ((thr - v9) < RISK_DELTA) {
        if (lane == 0) {
            int pos = atomicAdd(wcnt, 1);
            if (pos < WCAP) wlist[pos] = row;
        }
        return;
    }

    float p[4], psum = 0.f, pmu = 0.f;
    #pragma unroll
    for (int j = 0; j < 4; ++j) {
        p[j] = (lg[j] >= thr) ? __expf(lg[j] - mx) : 0.f;
        psum += p[j];
        pmu = fmaf(p[j], xlag[j], pmu);
    }
    #pragma unroll
    for (int off = 32; off >= 1; off >>= 1) {
        psum += __shfl_xor(psum, off, 64);
        pmu  += __shfl_xor(pmu,  off, 64);
    }
    float inv = 1.f / psum;
    float4 wo = make_float4(p[0] * inv, p[1] * inv, p[2] * inv, p[3] * inv);
    *reinterpret_cast<float4*>(&wOut[(size_t)row * LQ + l0]) = wo;
    if (lane == 0) muOut[row] = fmaf(pmu, inv, bias);
}

// ---------------- fixer: np-faithful fp32 pipeline (round-7 shell) ----------
// Arithmetic bit-identical to the round-4/5/7 arbiter-matcher: sequential f32 FMA
// ascending index per accumulator; __fadd_rn/__fmul_rn at materialization points.
// Changes vs round 7: #pragma unroll 1 on outer d2 loops (prevents the compiler
// hoisting all 128 loads -> VGPR blowup/spill seen in r7/r8) + explicit 2-deep
// double-buffered prefetch (wv0/wv1) so batch k+1 loads overlap batch k FMAs.
__global__ __launch_bounds__(256) void fixer(
    const float* __restrict__ x, const float* __restrict__ wk,
    const float* __restrict__ val_w, const float* __restrict__ conv_b,
    const float* __restrict__ ctx_b, const float* __restrict__ bias_w,
    const float* __restrict__ bias_b,
    const float* __restrict__ ctx_wT, const float* __restrict__ wqT,
    const float* __restrict__ conv_wT, const float* __restrict__ baseT,
    const int* __restrict__ wcnt, const int* __restrict__ wlist,
    float* __restrict__ muOut, float* __restrict__ wOut) {
    __shared__ float sxw[8][KCQ];
    __shared__ float sctxc[8][D];
    __shared__ float sctxp[8][D];
    __shared__ float sq[8][D];
    __shared__ float sqk[8][D];
    __shared__ float ssv[8];
    __shared__ float sbd[8];
    __shared__ float slog[8][LQ];
    __shared__ int   srow[8];

    int cnt = *wcnt;
    if (cnt > WCAP) cnt = WCAP;
    int ngroups = (cnt + 7) >> 3;
    int tid = threadIdx.x;

    for (int gi = blockIdx.x; gi < ngroups; gi += gridDim.x) {
        if (tid < 8) {
            int idx = gi * 8 + tid;
            if (idx >= cnt) idx = cnt - 1;   // pad with last row (duplicate write is benign)
            srow[tid] = wlist[idx];
        }
        __syncthreads();
        if (tid < 8 * KCQ) {
            int g = tid / KCQ, k = tid % KCQ;
            int row = srow[g]; int b = row >> 12, t = row & (TQ - 1);
            int ii = t - 8 + k;
            sxw[g][k] = (ii >= 0) ? x[b * TQ + ii] : 0.f;
        }
        __syncthreads();

        // stage 1: causal conv — sequential f32 FMA over k (9 taps)
        {
            int d = tid & (D - 1), gh = tid >> 7;
            float cw[KCQ];
            #pragma unroll
            for (int k = 0; k < KCQ; ++k) cw[k] = conv_wT[k * D + d];
            #pragma unroll 1
            for (int g = gh * 4; g < gh * 4 + 4; ++g) {
                float a = 0.f;
                #pragma unroll
                for (int k = 0; k < KCQ; ++k)
                    a = fmaf(cw[k], sxw[g][k], a);
                sctxc[g][d] = __fadd_rn(a, conv_b[d]);
            }
        }
        __syncthreads();

        // stage 2: ctx_proj — 4-row shared loads, double-buffered prefetch
        {
            int e = tid & (D - 1), gh = tid >> 7, g0 = gh * 4;
            float a0 = 0.f, a1 = 0.f, a2 = 0.f, a3 = 0.f;
            float wv0[16], wv1[16];
            #pragma unroll
            for (int u = 0; u < 16; ++u) wv0[u] = ctx_wT[u * D + e];
            #pragma unroll 1
            for (int d2 = 0; d2 < D; d2 += 32) {
                #pragma unroll
                for (int u = 0; u < 16; ++u) wv1[u] = ctx_wT[(d2 + 16 + u) * D + e];
                #pragma unroll
                for (int u = 0; u < 16; ++u) {
                    a0 = fmaf(wv0[u], sctxc[g0 + 0][d2 + u], a0);
                    a1 = fmaf(wv0[u], sctxc[g0 + 1][d2 + u], a1);
                    a2 = fmaf(wv0[u], sctxc[g0 + 2][d2 + u], a2);
                    a3 = fmaf(wv0[u], sctxc[g0 + 3][d2 + u], a3);
                }
                if (d2 + 32 < D) {
                    #pragma unroll
                    for (int u = 0; u < 16; ++u) wv0[u] = ctx_wT[(d2 + 32 + u) * D + e];
                }
                #pragma unroll
                for (int u = 0; u < 16; ++u) {
                    a0 = fmaf(wv1[u], sctxc[g0 + 0][d2 + 16 + u], a0);
                    a1 = fmaf(wv1[u], sctxc[g0 + 1][d2 + 16 + u], a1);
                    a2 = fmaf(wv1[u], sctxc[g0 + 2][d2 + 16 + u], a2);
                    a3 = fmaf(wv1[u], sctxc[g0 + 3][d2 + 16 + u], a3);
                }
            }
            float cb = ctx_b[e];
            sctxp[g0 + 0][e] = __fadd_rn(a0, cb);
            sctxp[g0 + 1][e] = __fadd_rn(a1, cb);
            sctxp[g0 + 2][e] = __fadd_rn(a2, cb);
            sctxp[g0 + 3][e] = __fadd_rn(a3, cb);
        }
        __syncthreads();

        // stage 3: q = ctx @ wq.T — same pattern with wqT
        {
            int a = tid & (D - 1), gh = tid >> 7, g0 = gh * 4;
            float a0 = 0.f, a1 = 0.f, a2 = 0.f, a3 = 0.f;
            float wv0[16], wv1[16];
            #pragma unroll
            for (int u = 0; u < 16; ++u) wv0[u] = wqT[u * D + a];
            #pragma unroll 1
            for (int e2 = 0; e2 < D; e2 += 32) {
                #pragma unroll
                for (int u = 0; u < 16; ++u) wv1[u] = wqT[(e2 + 16 + u) * D + a];
                #pragma unroll
                for (int u = 0; u < 16; ++u) {
                    a0 = fmaf(wv0[u], sctxp[g0 + 0][e2 + u], a0);
                    a1 = fmaf(wv0[u], sctxp[g0 + 1][e2 + u], a1);
                    a2 = fmaf(wv0[u], sctxp[g0 + 2][e2 + u], a2);
                    a3 = fmaf(wv0[u], sctxp[g0 + 3][e2 + u], a3);
                }
                if (e2 + 32 < D) {
                    #pragma unroll
                    for (int u = 0; u < 16; ++u) wv0[u] = wqT[(e2 + 32 + u) * D + a];
                }
                #pragma unroll
                for (int u = 0; u < 16; ++u) {
                    a0 = fmaf(wv1[u], sctxp[g0 + 0][e2 + 16 + u], a0);
                    a1 = fmaf(wv1[u], sctxp[g0 + 1][e2 + 16 + u], a1);
                    a2 = fmaf(wv1[u], sctxp[g0 + 2][e2 + 16 + u], a2);
                    a3 = fmaf(wv1[u], sctxp[g0 + 3][e2 + 16 + u], a3);
                }
            }
            sq[g0 + 0][a] = a0;
            sq[g0 + 1][a] = a1;
            sq[g0 + 2][a] = a2;
            sq[g0 + 3][a] = a3;
        }
        __syncthreads();

        // stage 4: qk = q @ wk — same pattern (wk is already column-coalesced)
        {
            int d = tid & (D - 1), gh = tid >> 7, g0 = gh * 4;
            float a0 = 0.f, a1 = 0.f, a2 = 0.f, a3 = 0.f;
            float wv0[16], wv1[16];
            #pragma unroll
            for (int u = 0; u < 16; ++u) wv0[u] = wk[u * D + d];
            #pragma unroll 1
            for (int a2i = 0; a2i < D; a2i += 32) {
                #pragma unroll
                for (int u = 0; u < 16; ++u) wv1[u] = wk[(a2i + 16 + u) * D + d];
                #pragma unroll
                for (int u = 0; u < 16; ++u) {
                    a0 = fmaf(wv0[u], sq[g0 + 0][a2i + u], a0);
                    a1 = fmaf(wv0[u], sq[g0 + 1][a2i + u], a1);
                    a2 = fmaf(wv0[u], sq[g0 + 2][a2i + u], a2);
                    a3 = fmaf(wv0[u], sq[g0 + 3][a2i + u], a3);
                }
                if (a2i + 32 < D) {
                    #pragma unroll
                    for (int u = 0; u < 16; ++u) wv0[u] = wk[(a2i + 32 + u) * D + d];
                }
                #pragma unroll
                for (int u = 0; u < 16; ++u) {
                    a0 = fmaf(wv1[u], sq[g0 + 0][a2i + 16 + u], a0);
                    a1 = fmaf(wv1[u], sq[g0 + 1][a2i + 16 + u], a1);
                    a2 = fmaf(wv1[u], sq[g0 + 2][a2i + 16 + u], a2);
                    a3 = fmaf(wv1[u], sq[g0 + 3][a2i + 16 + u], a3);
                }
            }
            sqk[g0 + 0][d] = a0;
            sqk[g0 + 1][d] = a1;
            sqk[g0 + 2][d] = a2;
            sqk[g0 + 3][d] = a3;
        }
        __syncthreads();

        // s = qk·val_w ; biasdot = ctxp·bias_w — sequential f32 FMA, batched loads
        if (tid < 8) {
            int g = tid;
            float a = 0.f;
            #pragma unroll 1
            for (int d2 = 0; d2 < D; d2 += 16) {
                float vv[16];
                #pragma unroll
                for (int u = 0; u < 16; ++u) vv[u] = val_w[d2 + u];
                #pragma unroll
                for (int u = 0; u < 16; ++u) a = fmaf(sqk[g][d2 + u], vv[u], a);
            }
            ssv[g] = a;
        } else if (tid < 16) {
            int g = tid - 8;
            float a = 0.f;
            #pragma unroll 1
            for (int e2 = 0; e2 < D; e2 += 16) {
                float vv[16];
                #pragma unroll
                for (int u = 0; u < 16; ++u) vv[u] = bias_w[e2 + u];
                #pragma unroll
                for (int u = 0; u < 16; ++u) a = fmaf(sctxp[g][e2 + u], vv[u], a);
            }
            sbd[g] = a;
        }
        __syncthreads();

        // logits: blog[l] = Σ_d baseT[d][l]·qk[d], 8 accs share double-buffered loads;
        // logit = f32(xlag*s) + blog
        {
            int l = tid;
            float c0 = 0.f, c1a = 0.f, c2 = 0.f, c3 = 0.f, c4 = 0.f, c5 = 0.f, c6 = 0.f, c7 = 0.f;
            float bd0[16], bd1[16];
            #pragma unroll
            for (int u = 0; u < 16; ++u) bd0[u] = baseT[u * LQ + l];
            #pragma unroll 1
            for (int d2 = 0; d2 < D; d2 += 32) {
                #pragma unroll
                for (int u = 0; u < 16; ++u) bd1[u] = baseT[(d2 + 16 + u) * LQ + l];
                #pragma unroll
                for (int u = 0; u < 16; ++u) {
                    c0 = fmaf(bd0[u], sqk[0][d2 + u], c0);
                    c1a = fmaf(bd0[u], sqk[1][d2 + u], c1a);
                    c2 = fmaf(bd0[u], sqk[2][d2 + u], c2);
                    c3 = fmaf(bd0[u], sqk[3][d2 + u], c3);
                    c4 = fmaf(bd0[u], sqk[4][d2 + u], c4);
                    c5 = fmaf(bd0[u], sqk[5][d2 + u], c5);
                    c6 = fmaf(bd0[u], sqk[6][d2 + u], c6);
                    c7 = fmaf(bd0[u], sqk[7][d2 + u], c7);
                }
                if (d2 + 32 < D) {
                    #pragma unroll
                    for (int u = 0; u < 16; ++u) bd0[u] = baseT[(d2 + 32 + u) * LQ + l];
                }
                #pragma unroll
                for (int u = 0; u < 16; ++u) {
                    c0 = fmaf(bd1[u], sqk[0][d2 + 16 + u], c0);
                    c1a = fmaf(bd1[u], sqk[1][d2 + 16 + u], c1a);
                    c2 = fmaf(bd1[u], sqk[2][d2 + 16 + u], c2);
                    c3 = fmaf(bd1[u], sqk[3][d2 + 16 + u], c3);
                    c4 = fmaf(bd1[u], sqk[4][d2 + 16 + u], c4);
                    c5 = fmaf(bd1[u], sqk[5][d2 + 16 + u], c5);
                    c6 = fmaf(bd1[u], sqk[6][d2 + 16 + u], c6);
                    c7 = fmaf(bd1[u], sqk[7][d2 + 16 + u], c7);
                }
            }
            float accs[8] = {c0, c1a, c2, c3, c4, c5, c6, c7};
            #pragma unroll
            for (int g = 0; g < 8; ++g) {
                int row = srow[g]; int b = row >> 12, t = row & (TQ - 1);
                int ii = t - 1 - l;
                float xl = (ii >= 0) ? x[b * TQ + ii] : 0.f;
                slog[g][l] = __fadd_rn(__fmul_rn(xl, ssv[g]), accs[g]);
            }
        }
        __syncthreads();

        // per-row f32 top-8 + f32 softmax + writes; wave handles 2 rows
        {
            int wave = tid >> 6, lane = tid & 63;
            #pragma unroll 1
            for (int gg = wave * 2; gg < wave * 2 + 2; ++gg) {
                float lv0 = slog[gg][lane], lv1 = slog[gg][lane + 64];
                float lv2 = slog[gg][lane + 128], lv3 = slog[gg][lane + 192];
                const float NEG_INF = -__builtin_inff();
                float w0 = lv0, w1 = lv1, w2 = lv2, w3 = lv3;
                float mx = 0.f, thr = 0.f;
                #pragma unroll
                for (int it = 0; it < 8; ++it) {
                    float lm = fmaxf(fmaxf(w0, w1), fmaxf(w2, w3));
                    float m = lm;
                    #pragma unroll
                    for (int off = 32; off >= 1; off >>= 1)
                        m = fmaxf(m, __shfl_xor(m, off, 64));
                    if (it == 0) mx = m;
                    thr = m;
                    if (it < 7) {
                        unsigned long long ball = __ballot(lm == m);
                        int leader = __ffsll(ball) - 1;
                        if (lane == leader) {
                            if (w0 == m)      w0 = NEG_INF;
                            else if (w1 == m) w1 = NEG_INF;
                            else if (w2 == m) w2 = NEG_INF;
                            else              w3 = NEG_INF;
                        }
                    }
                }
                int row = srow[gg]; int b = row >> 12, t = row & (TQ - 1);
                float p[4], xlg[4];
                double ps = 0.0;
                float lvs[4] = {lv0, lv1, lv2, lv3};
                #pragma unroll
                for (int j = 0; j < 4; ++j) {
                    int l = lane + 64 * j;
                    int ii = t - 1 - l;
                    xlg[j] = (ii >= 0) ? x[b * TQ + ii] : 0.f;
                    p[j] = (lvs[j] >= thr) ? (float)exp((double)__fsub_rn(lvs[j], mx)) : 0.f;
                    ps += (double)p[j];
                }
                #pragma unroll
                for (int off = 32; off >= 1; off >>= 1)
                    ps += __shfl_xor(ps, off, 64);
                float psf = (float)ps;
                double mud = 0.0;
                #pragma unroll
                for (int j = 0; j < 4; ++j) {
                    float wv = __fdiv_rn(p[j], psf);
                    wOut[(size_t)row * LQ + lane + 64 * j] = wv;
                    mud += (double)__fmul_rn(wv, xlg[j]);
                }
                #pragma unroll
                for (int off = 32; off >= 1; off >>= 1)
                    mud += __shfl_xor(mud, off, 64);
                if (lane == 0) {
                    float m1 = (float)mud;
                    m1 = __fadd_rn(m1, sbd[gg]);
                    m1 = __fadd_rn(m1, bias_b[0]);
                    muOut[row] = m1;
                }
            }
        }
        __syncthreads();
    }
}

extern "C" void kernel_launch(void* const* d_in, const int* in_sizes, int n_in,
                              void* d_out, int out_size, void* d_ws, size_t ws_size,
                              hipStream_t stream) {
    const float* x         = (const float*)d_in[0];
    const float* lag_embed = (const float*)d_in[1];
    const float* val_w     = (const float*)d_in[2];
    const float* val_b     = (const float*)d_in[3];
    const float* conv_w    = (const float*)d_in[4];
    const float* conv_b    = (const float*)d_in[5];
    const float* ctx_w     = (const float*)d_in[6];
    const float* ctx_b     = (const float*)d_in[7];
    const float* wq        = (const float*)d_in[8];
    const float* wk        = (const float*)d_in[9];
    const float* bias_w    = (const float*)d_in[10];
    const float* bias_b    = (const float*)d_in[11];

    char* wsb = (char*)d_ws;
    double* T2  = (double*)wsb;     // 16384 d
    double* g   = T2 + 16384;       // 1152
    double* u   = g + 1152;         // 128
    double* c1  = u + 128;          // 128
    double* gbT = c1 + 128;         // 2304
    double* cbv = gbT + 2304;       // 256
    double* cst = cbv + 256;        // 20   (f64 region ends @ byte 162976)
    int* wcnt  = (int*)(wsb + 163840);
    int* wlist = wcnt + 1;          // WCAP=16384 ints
    float* ctx_wT  = (float*)(wsb + 229504);   // 16384 f
    float* wqT     = ctx_wT + 16384;           // 16384 f
    float* conv_wT = wqT + 16384;              // 1152 f
    float* baseT   = conv_wT + 1152;           // 32768 f, ends @ byte 496256

    float* muOut = (float*)d_out;
    float* wOut  = muOut + BQ * TQ;

    hipLaunchKernelGGL(pk1, dim3(D + 2), dim3(256), 0, stream,
                       wk, wq, ctx_w, bias_w, conv_w, val_b, lag_embed,
                       T2, u, wcnt, ctx_wT, wqT, conv_wT, baseT);
    hipLaunchKernelGGL(pk2, dim3(D), dim3(D), 0, stream, T2, ctx_w, conv_w, conv_b, ctx_b, g, c1);
    hipLaunchKernelGGL(pk3, dim3(LQ + 1), dim3(D), 0, stream,
                       lag_embed, val_b, val_w, conv_w, conv_b, ctx_b, bias_w, bias_b,
                       g, c1, u, gbT, cbv, cst);
    hipLaunchKernelGGL(lag_main, dim3(BQ * TQ / 4), dim3(256), 0, stream,
                       x, gbT, cbv, cst, muOut, wOut, wcnt, wlist);
    hipLaunchKernelGGL(fixer, dim3(256), dim3(256), 0, stream,
                       x, wk, val_w, conv_b, ctx_b, bias_w, bias_b,
                       ctx_wT, wqT, conv_wT, baseT, wcnt, wlist, muOut, wOut);
}